// Round 8
// baseline (23.322 us; speedup 1.0000x reference)
//
#include <hip/hip_runtime.h>
#include <hip/hip_bf16.h>
#include <string.h>

#define NUM_CLASS 4096
#define HIDDEN    512
#define NGROUPS   64
#define BATCH     64

// ws layout (int offsets):
//   [10240..18431]    inv[2][4096]     (scatter fallback only)
//   float idx 16384+: tmp[kh][h][class 4096][b 64]
#define WS_INV   10240
#define TMP_OFF_F 16384
#define TMP_H_STRIDE (4096*64)       // floats per (kh,h) slice (1 MiB)
#define TMP_S_STRIDE (2*4096*64)     // floats per kh step (2 MiB)

typedef __attribute__((ext_vector_type(8))) short short8;
typedef __attribute__((ext_vector_type(4))) float f32x4;

__device__ __forceinline__ unsigned int pack2bf(float a, float b) {
    __hip_bfloat16 ha = __float2bfloat16(a), hb = __float2bfloat16(b);
    unsigned short ua, ub;
    memcpy(&ua, &ha, 2); memcpy(&ub, &hb, 2);
    return (unsigned int)ua | ((unsigned int)ub << 16);
}

// only needed for the scatter fallback (tiny ws): builds inv permutation
__global__ __launch_bounds__(1024) void prep_inv_kernel(
    const int* __restrict__ co_idx, const int* __restrict__ cl_idx,
    int* __restrict__ ws)
{
    int tid = threadIdx.x;
    for (int v = tid; v < 2 * NUM_CLASS; v += 1024) {
        int h = v >> 12, c = v & (NUM_CLASS - 1);
        const int* idx = h ? cl_idx : co_idx;
        ws[WS_INV + h * NUM_CLASS + idx[c]] = c;
    }
}

// chunk-slot stage1: block = (chunk of 64 classes, h, kh). No worklist.
// Each block finds its own group-segments via ballot, runs one MFMA pass
// per segment, merges valid slots into ftile, writes dense class-indexed tmp.
template<int KS, bool SCATTER>
__global__ __launch_bounds__(256, 4) void gwl_stage1(
    const float* __restrict__ x,
    const float* __restrict__ co_W, const float* __restrict__ cl_W,
    const float* __restrict__ co_b, const float* __restrict__ cl_b,
    const int* __restrict__ co_gof, const int* __restrict__ cl_gof,
    int* __restrict__ ws, float* __restrict__ out)
{
    const int NCH = 8 / KS;          // k-chunks of 64 per block
    const int nblk = 128 * KS;       // 64 chunks * 2 h * KS
    const int chunk = nblk >> 3;
    int bid = blockIdx.x;
    int swz = (bid & 7) * chunk + (bid >> 3);
    int cid = swz & 63;              // class chunk id
    int hk  = swz >> 6;
    int h   = hk & 1;
    int kh  = hk >> 1;
    int c0  = cid * 64;

    const float* Wp  = h ? cl_W : co_W;
    const int*   gof = h ? cl_gof : co_gof;

    __shared__ __align__(16) unsigned short Xs[64][72];
    __shared__ __align__(16) unsigned short Wls[64][72];
    __shared__ float ftile[64][65];
    __shared__ int s_seg_lo[65];
    __shared__ int s_seg_g[64];
    __shared__ int s_nseg;

    int tid = threadIdx.x;
    int l = tid & 63, w = tid >> 6;

    // --- segment scan (wave 0) ---
    if (tid < 64) {
        int gi = gof[c0 + tid];
        int prev = (tid == 0) ? -1 : gof[c0 + tid - 1];
        bool is_start = (gi != prev);
        unsigned long long m = __ballot(is_start);
        int segidx = (int)__popcll(m & ((1ull << tid) - 1ull));
        if (is_start) { s_seg_lo[segidx] = tid; s_seg_g[segidx] = gi; }
        if (tid == 0) {
            int ns = (int)__popcll(m);
            s_nseg = ns;
            s_seg_lo[ns] = 64;
        }
    }

    int rowq[4], kvq[4];
    #pragma unroll
    for (int q = 0; q < 4; ++q) {
        int v = q * 256 + tid;
        rowq[q] = v >> 4;
        kvq[q]  = v & 15;
    }

    float4 rxA[4], rwA[4], rxB[4], rwB[4];
    f32x4 acc[4];
    #pragma unroll
    for (int i = 0; i < 4; ++i) acc[i] = (f32x4)(0.0f);

    const int kbase = kh * (HIDDEN / KS);

#define LOADC(S, RX, RW, NEEDW) do {                                                \
    int si_ = (S) / NCH, t_ = (S) % NCH;                                            \
    int k0_ = kbase + t_ * 64;                                                      \
    int xr_ = h * 64 + s_seg_g[si_];                                                \
    _Pragma("unroll")                                                               \
    for (int q = 0; q < 4; ++q) {                                                   \
        RX[q] = *(const float4*)(x + rowq[q] * 65536 + xr_ * 512 + k0_ + kvq[q]*4); \
        if (NEEDW)                                                                  \
            RW[q] = *(const float4*)(Wp + (c0 + rowq[q]) * 512 + k0_ + kvq[q] * 4); \
    } } while (0)

#define STOREC(RX, RW, NEEDW) do {                                                  \
    _Pragma("unroll")                                                               \
    for (int q = 0; q < 4; ++q) {                                                   \
        unsigned int x0 = pack2bf(RX[q].x, RX[q].y);                                \
        unsigned int x1 = pack2bf(RX[q].z, RX[q].w);                                \
        *(uint2*)&Xs[rowq[q]][kvq[q] * 4] = make_uint2(x0, x1);                     \
        if (NEEDW) {                                                                \
            unsigned int w0 = pack2bf(RW[q].x, RW[q].y);                            \
            unsigned int w1 = pack2bf(RW[q].z, RW[q].w);                            \
            *(uint2*)&Wls[rowq[q]][kvq[q] * 4] = make_uint2(w0, w1);                \
        }                                                                           \
    } } while (0)

#define COMPUTEC() do {                                                             \
    _Pragma("unroll")                                                               \
    for (int kq = 0; kq < 2; ++kq) {                                                \
        int koff = kq * 32 + (l >> 4) * 8;                                          \
        short8 bfrag = *(const short8*)&Wls[w * 16 + (l & 15)][koff];               \
        _Pragma("unroll")                                                           \
        for (int i = 0; i < 4; ++i) {                                               \
            short8 afrag = *(const short8*)&Xs[16 * i + (l & 15)][koff];            \
            acc[i] = __builtin_amdgcn_mfma_f32_16x16x32_bf16(afrag, bfrag, acc[i],  \
                                                             0, 0, 0);              \
        }                                                                           \
    } } while (0)

    __syncthreads();   // segment data ready
    int nseg = s_nseg;
    int nsteps = nseg * NCH;
    int slotw = w * 16 + (l & 15);

    LOADC(0, rxA, rwA, true);
    STOREC(rxA, rwA, true);
    __syncthreads();

    #pragma unroll 1
    for (int s = 0; s < nsteps; ++s) {
        bool nxt = (s + 1 < nsteps);
        const bool needW = (NCH > 1);   // NCH==1: W staged once at step 0
        if (nxt) {
            if (s & 1) LOADC(s + 1, rxA, rwA, needW);
            else       LOADC(s + 1, rxB, rwB, needW);
        }
        COMPUTEC();
        if ((s % NCH) == NCH - 1) {
            int si = s / NCH;
            int lo = s_seg_lo[si], hi = s_seg_lo[si + 1];
            if (slotw >= lo && slotw < hi) {
                #pragma unroll
                for (int i = 0; i < 4; ++i)
                    #pragma unroll
                    for (int r = 0; r < 4; ++r)
                        ftile[slotw][16 * i + (l >> 4) * 4 + r] = acc[i][r];
            }
            #pragma unroll
            for (int i = 0; i < 4; ++i) acc[i] = (f32x4)(0.0f);
        }
        __syncthreads();
        if (nxt) {
            if (s & 1) STOREC(rxA, rwA, needW);
            else       STOREC(rxB, rwB, needW);
            __syncthreads();
        }
    }

    if (!SCATTER) {
        float* tmph = (float*)ws + TMP_OFF_F + (size_t)(kh * 2 + h) * TMP_H_STRIDE;
        #pragma unroll
        for (int p = 0; p < 4; ++p) {
            int f = p * 256 + tid;
            int slot = f >> 4, b4 = (f & 15) * 4;
            *(float4*)&tmph[(size_t)(c0 + slot) * 64 + b4] =
                *(const float4*)&ftile[slot][b4];
        }
    } else {
        const float* bias = h ? cl_b : co_b;
        const int*   inv  = ws + WS_INV + h * NUM_CLASS;
        float* outh = out + (size_t)h * BATCH * NUM_CLASS;
        #pragma unroll
        for (int p = 0; p < 4; ++p) {
            int f = p * 256 + tid;
            int slot = f >> 4, b4 = (f & 15) * 4;
            int c = c0 + slot;
            int oc = inv[c];
            float bb = bias[c];
            #pragma unroll
            for (int e = 0; e < 4; ++e)
                outh[(b4 + e) * 4096 + oc] = ftile[slot][b4 + e] + bb;
        }
    }
#undef LOADC
#undef STOREC
#undef COMPUTEC
}

// gather-free permute: per block = 64 output columns x 64 batch rows.
// each wave-iteration reads KS contiguous 64-float (256B) tmp runs.
template<int KS>
__global__ __launch_bounds__(256) void gwl_permute(
    const int* __restrict__ ws,
    const float* __restrict__ co_b, const float* __restrict__ cl_b,
    const int* __restrict__ co_idx, const int* __restrict__ cl_idx,
    float* __restrict__ out)
{
    int jc = blockIdx.x;   // 0..63 : output column chunk
    int h  = blockIdx.y;   // 0..1
    const float* bias = h ? cl_b : co_b;
    const int*   idx  = h ? cl_idx : co_idx;
    const float* tmph = (const float*)ws + TMP_OFF_F + (size_t)h * TMP_H_STRIDE;

    __shared__ float tile[64][65];
    int tid = threadIdx.x;
    int lane = tid & 63, w = tid >> 6;

    #pragma unroll
    for (int u = 0; u < 16; ++u) {
        int jj = u * 4 + w;               // 0..63, wave-uniform
        int j  = jc * 64 + jj;
        int c  = idx[j];                  // wave-uniform scalar
        float v = bias[c];
        #pragma unroll
        for (int s = 0; s < KS; ++s)
            v += tmph[(size_t)s * TMP_S_STRIDE + (size_t)c * 64 + lane];
        tile[lane][jj] = v;               // [b][j], stride 65 -> conflict-free
    }
    __syncthreads();

    #pragma unroll
    for (int p = 0; p < 4; ++p) {
        int f = p * 256 + tid;
        int b = f >> 4, j4 = (f & 15) * 4;
        *(float4*)&out[((size_t)h * 64 + b) * 4096 + jc * 64 + j4] =
            *(const float4*)&tile[b][j4];
    }
}

extern "C" void kernel_launch(void* const* d_in, const int* in_sizes, int n_in,
                              void* d_out, int out_size, void* d_ws, size_t ws_size,
                              hipStream_t stream)
{
    (void)in_sizes; (void)n_in; (void)out_size;
    const float* x      = (const float*)d_in[0];
    const float* co_W   = (const float*)d_in[1];
    const float* cl_W   = (const float*)d_in[2];
    const float* co_b   = (const float*)d_in[3];
    const float* cl_b   = (const float*)d_in[4];
    const int*   co_gof = (const int*)d_in[5];
    const int*   cl_gof = (const int*)d_in[6];
    const int*   co_idx = (const int*)d_in[7];
    const int*   cl_idx = (const int*)d_in[8];
    int*   ws  = (int*)d_ws;
    float* out = (float*)d_out;

    const size_t base  = (size_t)TMP_OFF_F * 4;
    const size_t slice = (size_t)TMP_S_STRIDE * 4;   // 2 MiB per kh step

    if (ws_size >= base + 8 * slice) {
        hipLaunchKernelGGL((gwl_stage1<8, false>), dim3(1024), dim3(256), 0, stream,
                           x, co_W, cl_W, co_b, cl_b, co_gof, cl_gof, ws, out);
        hipLaunchKernelGGL((gwl_permute<8>), dim3(64, 2), dim3(256), 0, stream,
                           ws, co_b, cl_b, co_idx, cl_idx, out);
    } else if (ws_size >= base + 4 * slice) {
        hipLaunchKernelGGL((gwl_stage1<4, false>), dim3(512), dim3(256), 0, stream,
                           x, co_W, cl_W, co_b, cl_b, co_gof, cl_gof, ws, out);
        hipLaunchKernelGGL((gwl_permute<4>), dim3(64, 2), dim3(256), 0, stream,
                           ws, co_b, cl_b, co_idx, cl_idx, out);
    } else if (ws_size >= base + 2 * slice) {
        hipLaunchKernelGGL((gwl_stage1<2, false>), dim3(256), dim3(256), 0, stream,
                           x, co_W, cl_W, co_b, cl_b, co_gof, cl_gof, ws, out);
        hipLaunchKernelGGL((gwl_permute<2>), dim3(64, 2), dim3(256), 0, stream,
                           ws, co_b, cl_b, co_idx, cl_idx, out);
    } else if (ws_size >= base + 1 * slice) {
        hipLaunchKernelGGL((gwl_stage1<1, false>), dim3(128), dim3(256), 0, stream,
                           x, co_W, cl_W, co_b, cl_b, co_gof, cl_gof, ws, out);
        hipLaunchKernelGGL((gwl_permute<1>), dim3(64, 2), dim3(256), 0, stream,
                           ws, co_b, cl_b, co_idx, cl_idx, out);
    } else {
        hipLaunchKernelGGL(prep_inv_kernel, dim3(1), dim3(1024), 0, stream,
                           co_idx, cl_idx, ws);
        hipLaunchKernelGGL((gwl_stage1<1, true>), dim3(128), dim3(256), 0, stream,
                           x, co_W, cl_W, co_b, cl_b, co_gof, cl_gof, ws, out);
    }
}